// Round 13
// baseline (139.836 us; speedup 1.0000x reference)
//
#include <hip/hip_runtime.h>
#include <hip/hip_bf16.h>

#define D_MODEL 256
#define N_HEADS 8
#define D_HEAD 32
#define N_LEVELS 4
#define N_POINTS 4
#define LEN_IN 21760
#define N_BATCH 8
#define LEN_Q 1000

typedef __attribute__((ext_vector_type(8))) short short8;
typedef __attribute__((ext_vector_type(4))) float f32x4;
typedef __attribute__((ext_vector_type(4))) unsigned int u32x4;

typedef const __attribute__((address_space(1))) void* gp1;
typedef __attribute__((address_space(3))) void* lp3;

__device__ __forceinline__ unsigned short f2bf(float f) {
    unsigned int u = __float_as_uint(f);
    u += 0x7FFFu + ((u >> 16) & 1u);   // RNE
    return (unsigned short)(u >> 16);
}
__device__ __forceinline__ float bf2f(unsigned short s) {
    return __uint_as_float(((unsigned int)s) << 16);
}
__device__ __forceinline__ unsigned int cvtpk(float lo, float hi) {
    unsigned int r;
    asm("v_cvt_pk_bf16_f32 %0, %1, %2" : "=v"(r) : "v"(lo), "v"(hi));
    return r;
}

// ---------------------------------------------------------------------------
// prep:
//   WtVp [8][16][64][8] bf16  <- W_val^T packed MFMA-fragment-major
//        elem(ks,nf,lane,j) = W_val[k=ks*32+(lane>>4)*8+j][col=nf*16+(lane&15)]
//   WtC  [384][256] bf16      <- [W_off | W_attn]^T row-major
//   WtO  [256][256] bf16      <- W_out^T row-major
//   bcat [384] f32            <- [b_off | b_attn]
// ---------------------------------------------------------------------------
__global__ __launch_bounds__(256) void prep_kernel(
    const float* __restrict__ Wv, const float* __restrict__ Wo,
    const float* __restrict__ Wa, const float* __restrict__ Wu,
    const float* __restrict__ boff, const float* __restrict__ battn,
    unsigned short* __restrict__ WtVp, unsigned short* __restrict__ WtC,
    unsigned short* __restrict__ WtO, float* __restrict__ bcat)
{
    int idx = blockIdx.x * 256 + threadIdx.x;
    if (idx < 65536) {
        int j = idx & 7, lane = (idx >> 3) & 63, nf = (idx >> 9) & 15, ks = idx >> 13;
        int col = nf * 16 + (lane & 15);
        int k = ks * 32 + (lane >> 4) * 8 + j;
        WtVp[idx] = f2bf(Wv[k * 256 + col]);
    } else if (idx < 65536 + 98304) {
        int j = idx - 65536;
        int n = j >> 8, k = j & 255;
        float s = (n < 256) ? Wo[k * 256 + n] : Wa[k * 128 + (n - 256)];
        WtC[j] = f2bf(s);
    } else if (idx < 65536 + 98304 + 65536) {
        int j = idx - (65536 + 98304);
        int n = j >> 8, k = j & 255;
        WtO[j] = f2bf(Wu[k * 256 + n]);
    } else if (idx < 65536 + 98304 + 65536 + 384) {
        int j = idx - (65536 + 98304 + 65536);
        bcat[j] = (j < 256) ? boff[j] : battn[j - 256];
    }
}

// ---------------------------------------------------------------------------
// Value GEMM v7 (persistent, cross-tile pipeline):
// C_bf16[174080][256] = A_f32[174080][256] @ W_val + bias
// Grid 680 blocks (ALL co-resident at 32KB LDS / ~128 VGPR -> 4 blk/CU);
// each block owns 4 consecutive m-tiles of 64 rows = 256 rows. The v4 inner
// schedule (BK=64, 2x16KB dbuf, B same-iter, counted vmcnt) runs as ONE
// uninterrupted 16-step pipeline across tile boundaries: stage for tile i+1
// kt=0 issues during tile i kt=3. Fill paid once per 16 steps, not per 4.
// Per-iter FIFO (exact): issue [B(tau) x8][S(tau+1) x4]; vmcnt(12) leaves
// exactly those 12, drains S(tau) (issued last iter) AND any epilogue
// stores from a tile boundary (harmless flush; count stays exact because
// vmcnt counts the NEWEST N). Tail tau=15: vmcnt(8) drains S(15).
// Granule XOR swizzle (16B granules, 16/row of 256B): physical pg holds
// logical cg = pg ^ (row&15); applied on gload_lds SOURCE (LDS dest linear,
// m104/m173), re-applied on ds_read. f32->bf16 via v_cvt_pk_bf16_f32.
// ---------------------------------------------------------------------------
__global__ __launch_bounds__(256) void gemm_value(
    const float* __restrict__ A,
    const unsigned short* __restrict__ Bp,   // [8][16][64][8] bf16
    const float* __restrict__ bias,
    unsigned short* __restrict__ C)
{
    __shared__ __align__(16) float lds[2][4096];   // 2 x 16KB = 64 rows x 256B

    const int tid = threadIdx.x;
    const int wave = tid >> 6, lane = tid & 63;
    const int lhi = lane >> 4, llo = lane & 15;
    const size_t rowBlk = (size_t)blockIdx.x * 256;   // 4 m-tiles x 64 rows

    // staging: instr i covers rows srow+{0,16,32,48}; thread t writes LDS
    // granule t (+256,+512,+768). row's physical granule pg holds logical
    // cg = pg ^ (row&15) -> source col-granule = (tid&15)^(srow&15).
    const int srow = tid >> 4;                        // 0..15
    const int scg = (tid & 15) ^ (srow & 15);
    const char* Ab = (const char*)(A + rowBlk * 256);
    const size_t src0 = (size_t)srow * 1024 + (size_t)scg * 16;

#define STG(bi, tile, kt) { \
    const char* s_ = Ab + (size_t)(tile) * 65536 + (size_t)(kt) * 256 + src0; \
    char* d_ = (char*)&lds[bi][0] + tid * 16; \
    __builtin_amdgcn_global_load_lds((gp1)(const void*)(s_),         (lp3)(d_),         16, 0, 0); \
    __builtin_amdgcn_global_load_lds((gp1)(const void*)(s_ + 16384), (lp3)(d_ + 4096),  16, 0, 0); \
    __builtin_amdgcn_global_load_lds((gp1)(const void*)(s_ + 32768), (lp3)(d_ + 8192),  16, 0, 0); \
    __builtin_amdgcn_global_load_lds((gp1)(const void*)(s_ + 49152), (lp3)(d_ + 12288), 16, 0, 0); }

    f32x4 acc[4][4];
#pragma unroll
    for (int mf = 0; mf < 4; ++mf)
#pragma unroll
        for (int n = 0; n < 4; ++n)
            acc[mf][n] = (f32x4){0.f, 0.f, 0.f, 0.f};

    float bb[4];
#pragma unroll
    for (int n = 0; n < 4; ++n) bb[n] = bias[wave * 64 + n * 16 + llo];

    STG(0, 0, 0);   // prologue stage

#pragma unroll
    for (int tau = 0; tau < 16; ++tau) {
        const int tile = tau >> 2, kt = tau & 3, cur = tau & 1;

        // B fragments for this k-step (L1-hot after tile 0), issued first
        short8 b[2][4];
#pragma unroll
        for (int ksi = 0; ksi < 2; ++ksi)
#pragma unroll
            for (int n = 0; n < 4; ++n)
                b[ksi][n] = *reinterpret_cast<const short8*>(
                    Bp + ((size_t)((kt * 2 + ksi) * 16 + wave * 4 + n) * 64 + lane) * 8);

        // stage next step (crosses tile boundary seamlessly)
        if (tau < 15) {
            const int nt = tau + 1;
            STG(nt & 1, nt >> 2, nt & 3);
        }

        __builtin_amdgcn_sched_barrier(0);
        if (tau < 15) asm volatile("s_waitcnt vmcnt(12)" ::: "memory");
        else          asm volatile("s_waitcnt vmcnt(8)" ::: "memory");
        __builtin_amdgcn_sched_barrier(0);
        __builtin_amdgcn_s_barrier();
        __builtin_amdgcn_sched_barrier(0);

        // compute: 4 mf x 2 ksi x 4 n MFMAs; A frags via swizzled ds_read
#pragma unroll
        for (int mf = 0; mf < 4; ++mf) {
            const int row = mf * 16 + llo;
            const char* rbase = (const char*)&lds[cur][0] + row * 256;
#pragma unroll
            for (int ksi = 0; ksi < 2; ++ksi) {
                const int cg0 = ksi * 8 + lhi * 2;
                f32x4 flo = *reinterpret_cast<const f32x4*>(rbase + ((cg0 ^ llo) << 4));
                f32x4 fhi = *reinterpret_cast<const f32x4*>(rbase + (((cg0 + 1) ^ llo) << 4));
                u32x4 pk;
                pk[0] = cvtpk(flo[0], flo[1]);
                pk[1] = cvtpk(flo[2], flo[3]);
                pk[2] = cvtpk(fhi[0], fhi[1]);
                pk[3] = cvtpk(fhi[2], fhi[3]);
                short8 af = __builtin_bit_cast(short8, pk);
#pragma unroll
                for (int n = 0; n < 4; ++n)
                    acc[mf][n] = __builtin_amdgcn_mfma_f32_16x16x32_bf16(
                        af, b[ksi][n], acc[mf][n], 0, 0, 0);
            }
        }

        __builtin_amdgcn_sched_barrier(0);
        __builtin_amdgcn_s_barrier();
        __builtin_amdgcn_sched_barrier(0);

        // tile-boundary epilogue (stores flushed by next counted wait)
        if (kt == 3) {
#pragma unroll
            for (int mf = 0; mf < 4; ++mf) {
                const int row0 = (int)rowBlk + tile * 64 + mf * 16 + lhi * 4;
#pragma unroll
                for (int n = 0; n < 4; ++n) {
                    const int col = wave * 64 + n * 16 + llo;
                    unsigned int u01 = cvtpk(acc[mf][n][0] + bb[n], acc[mf][n][1] + bb[n]);
                    unsigned int u23 = cvtpk(acc[mf][n][2] + bb[n], acc[mf][n][3] + bb[n]);
                    C[(size_t)(row0 + 0) * 256 + col] = (unsigned short)(u01 & 0xFFFFu);
                    C[(size_t)(row0 + 1) * 256 + col] = (unsigned short)(u01 >> 16);
                    C[(size_t)(row0 + 2) * 256 + col] = (unsigned short)(u23 & 0xFFFFu);
                    C[(size_t)(row0 + 3) * 256 + col] = (unsigned short)(u23 >> 16);
                    acc[mf][n] = (f32x4){0.f, 0.f, 0.f, 0.f};
                }
            }
        }
    }
#undef STG
}

// ---------------------------------------------------------------------------
// Generic K=256 MFMA GEMM, BM=16: C[M][N] = A[M][256] @ Wt^T + bias
// ---------------------------------------------------------------------------
template<int NF, bool ABF16, bool OBF16>
__global__ __launch_bounds__(256) void gemm_k256(
    const void* __restrict__ Av, const unsigned short* __restrict__ Wt,
    const float* __restrict__ bias, void* __restrict__ Cv)
{
    const int wave = threadIdx.x >> 6;
    const int lane = threadIdx.x & 63;
    const int lhi = lane >> 4, llo = lane & 15;
    const int mBase = blockIdx.x * 16;
    const int colBase = wave * (NF * 16);
    const int N = NF * 64;

    f32x4 acc[NF];
#pragma unroll
    for (int n = 0; n < NF; ++n)
        acc[n] = (f32x4){0.f, 0.f, 0.f, 0.f};

#pragma unroll
    for (int ks = 0; ks < 8; ++ks) {
        const int kk = ks * 32 + lhi * 8;
        short8 a;
        if (ABF16) {
            a = *reinterpret_cast<const short8*>(
                (const unsigned short*)Av + (size_t)(mBase + llo) * 256 + kk);
        } else {
            const float* ap = (const float*)Av + (size_t)(mBase + llo) * 256 + kk;
            f32x4 f0 = *reinterpret_cast<const f32x4*>(ap);
            f32x4 f1 = *reinterpret_cast<const f32x4*>(ap + 4);
            u32x4 pk;
            pk[0] = cvtpk(f0[0], f0[1]);
            pk[1] = cvtpk(f0[2], f0[3]);
            pk[2] = cvtpk(f1[0], f1[1]);
            pk[3] = cvtpk(f1[2], f1[3]);
            a = __builtin_bit_cast(short8, pk);
        }
        short8 b[NF];
#pragma unroll
        for (int n = 0; n < NF; ++n) {
            const unsigned short* bp =
                Wt + (size_t)(colBase + n * 16 + llo) * 256 + kk;
            b[n] = *reinterpret_cast<const short8*>(bp);
        }
#pragma unroll
        for (int n = 0; n < NF; ++n)
            acc[n] = __builtin_amdgcn_mfma_f32_16x16x32_bf16(
                a, b[n], acc[n], 0, 0, 0);
    }

    const int row0 = mBase + lhi * 4;
#pragma unroll
    for (int n = 0; n < NF; ++n) {
        const int col = colBase + n * 16 + llo;
        const float bb = bias[col];
#pragma unroll
        for (int r = 0; r < 4; ++r) {
            float v = acc[n][r] + bb;
            size_t idx = (size_t)(row0 + r) * N + col;
            if (OBF16) ((unsigned short*)Cv)[idx] = f2bf(v);
            else       ((float*)Cv)[idx] = v;
        }
    }
}

// ---------------------------------------------------------------------------
// Sampling v5: task-per-lane; float2 merged proj/refp loads; gathers issued
// before the softmax shfl chain (softmax hides under gather latency).
// ---------------------------------------------------------------------------
__global__ __launch_bounds__(512) void ms_sample_kernel(
    const unsigned short* __restrict__ value,  // [8*21760][256] bf16
    const float* __restrict__ proj,            // [8000][384] f32
    const float* __restrict__ refp,            // [8][1000][4][2] f32
    unsigned short* __restrict__ out_h)        // [8000][256] bf16
{
    const int bid = blockIdx.x;
    const int b = bid & 7;                     // XCD-pinned batch
    const int q = bid >> 3;
    const int bq = b * LEN_Q + q;

    const int h = threadIdx.x >> 6;            // 0..7
    const int lane = threadIdx.x & 63;
    const int task = lane >> 2;                // 0..15 = l*4+p
    const int l = task >> 2;
    const int qd = lane & 3;                   // dim quarter

    const float* prow = proj + (size_t)bq * 384;

    // ---- address math for this lane's sample ----
    const int Wl = 128 >> l;
    const int st = (65536 - (65536 >> (l << 1))) / 3;  // level start row

    const float2 dxy = *reinterpret_cast<const float2*>(prow + h * 32 + 2 * task);
    const float2 rxy = *reinterpret_cast<const float2*>(refp + ((size_t)bq * 4 + l) * 2);

    const float Wlf = (float)Wl;
    const float x = rxy.x * Wlf + dxy.x - 0.5f;
    const float y = rxy.y * Wlf + dxy.y - 0.5f;
    const float x0f = floorf(x), y0f = floorf(y);
    const int x0 = (int)x0f, y0 = (int)y0f;
    const float wx1 = x - x0f, wy1 = y - y0f;
    const float wx0 = 1.f - wx1, wy0 = 1.f - wy1;

    const int x0c = min(max(x0, 0), Wl - 1);
    const int x1c = min(max(x0 + 1, 0), Wl - 1);
    const int y0c = min(max(y0, 0), Wl - 1);
    const int y1c = min(max(y0 + 1, 0), Wl - 1);
    const float fx0 = (x0 >= 0 && x0 < Wl) ? 1.f : 0.f;
    const float fx1 = (x0 + 1 >= 0 && x0 + 1 < Wl) ? 1.f : 0.f;
    const float fy0 = (y0 >= 0 && y0 < Wl) ? 1.f : 0.f;
    const float fy1 = (y0 + 1 >= 0 && y0 + 1 < Wl) ? 1.f : 0.f;

    const int rr0 = st + y0c * Wl, rr1 = st + y1c * Wl;
    const int r00 = rr0 + x0c, r01 = rr0 + x1c;
    const int r10 = rr1 + x0c, r11 = rr1 + x1c;

    // ---- issue all 4 gathers ----
    const char* vb = (const char*)value + (size_t)b * LEN_IN * 512
                   + h * 64 + qd * 16;
    u32x4 v0 = *reinterpret_cast<const u32x4*>(vb + (size_t)r00 * 512);
    u32x4 v1 = *reinterpret_cast<const u32x4*>(vb + (size_t)r01 * 512);
    u32x4 v2 = *reinterpret_cast<const u32x4*>(vb + (size_t)r10 * 512);
    u32x4 v3 = *reinterpret_cast<const u32x4*>(vb + (size_t)r11 * 512);

    // ---- softmax under gather shadow ----
    float lg = prow[256 + h * 16 + (lane & 15)];
    float mx = lg;
    mx = fmaxf(mx, __shfl_xor(mx, 1, 16));
    mx = fmaxf(mx, __shfl_xor(mx, 2, 16));
    mx = fmaxf(mx, __shfl_xor(mx, 4, 16));
    mx = fmaxf(mx, __shfl_xor(mx, 8, 16));
    float e = __expf(lg - mx);
    float den = e;
    den += __shfl_xor(den, 1, 16);
    den += __shfl_xor(den, 2, 16);
    den += __shfl_xor(den, 4, 16);
    den += __shfl_xor(den, 8, 16);
    const float wsm = e / den;
    const float ws = __shfl(wsm, task, 16);    // this lane's task weight

    float wgt[4];
    wgt[0] = ws * wy0 * wx0 * fy0 * fx0;
    wgt[1] = ws * wy0 * wx1 * fy0 * fx1;
    wgt[2] = ws * wy1 * wx0 * fy1 * fx0;
    wgt[3] = ws * wy1 * wx1 * fy1 * fx1;

    // ---- weighted accumulate: 8 dims per lane ----
    float acc[8];
#pragma unroll
    for (int j = 0; j < 8; ++j) acc[j] = 0.f;
#pragma unroll
    for (int n = 0; n < 4; ++n) {
        const u32x4 v = (n == 0) ? v0 : (n == 1) ? v1 : (n == 2) ? v2 : v3;
        const float wn = wgt[n];
#pragma unroll
        for (int j = 0; j < 4; ++j) {
            const unsigned int u = v[j];
            acc[2 * j]     += wn * bf2f((unsigned short)(u & 0xFFFFu));
            acc[2 * j + 1] += wn * bf2f((unsigned short)(u >> 16));
        }
    }

    // ---- reduce over the 16 tasks (stride-4 lane sets) ----
#pragma unroll
    for (int j = 0; j < 8; ++j) {
        acc[j] += __shfl_xor(acc[j], 4, 64);
        acc[j] += __shfl_xor(acc[j], 8, 64);
        acc[j] += __shfl_xor(acc[j], 16, 64);
        acc[j] += __shfl_xor(acc[j], 32, 64);
    }

    if (task == 0) {
        u32x4 o;
#pragma unroll
        for (int j = 0; j < 4; ++j)
            o[j] = (unsigned int)f2bf(acc[2 * j]) |
                   ((unsigned int)f2bf(acc[2 * j + 1]) << 16);
        *reinterpret_cast<u32x4*>(
            out_h + (size_t)bq * 256 + h * 32 + qd * 8) = o;
    }
}

// ---------------------------------------------------------------------------
extern "C" void kernel_launch(void* const* d_in, const int* in_sizes, int n_in,
                              void* d_out, int out_size, void* d_ws, size_t ws_size,
                              hipStream_t stream)
{
    const float* query  = (const float*)d_in[0];
    const float* refp   = (const float*)d_in[1];
    const float* inpf   = (const float*)d_in[2];
    const float* W_off  = (const float*)d_in[5];
    const float* b_off  = (const float*)d_in[6];
    const float* W_attn = (const float*)d_in[7];
    const float* b_attn = (const float*)d_in[8];
    const float* W_val  = (const float*)d_in[9];
    const float* b_val  = (const float*)d_in[10];
    const float* W_out  = (const float*)d_in[11];
    const float* b_out  = (const float*)d_in[12];

    char* ws = (char*)d_ws;
    unsigned short* value = (unsigned short*)(ws);                    // 89,128,960 B
    float*          proj  = (float*)(ws + 89128960);                  // 12,288,000 B
    unsigned short* out_h = (unsigned short*)(ws + 89128960 + 12288000); // 4,096,000 B
    unsigned short* WtVp  = (unsigned short*)(ws + 109608960);        //    131,072 B
    unsigned short* WtC   = (unsigned short*)(ws + 109740032);        //    196,608 B
    unsigned short* WtO   = (unsigned short*)(ws + 109936640);        //    131,072 B
    float*          bcat  = (float*)(ws + 110067712);                 //      1,536 B

    prep_kernel<<<898, 256, 0, stream>>>(W_val, W_off, W_attn, W_out,
                                         b_off, b_attn, WtVp, WtC, WtO, bcat);

    // value = input_flatten @ W_val + b_val -> bf16 [174080][256]
    // persistent: 680 blocks x 4 m-tiles x 64 rows = 174080
    gemm_value<<<680, 256, 0, stream>>>(inpf, WtVp, b_val, value);

    // proj = query @ [W_off|W_attn] + bias -> f32 [8000][384]
    gemm_k256<6, false, false><<<(N_BATCH * LEN_Q) / 16, 256, 0, stream>>>(
        query, WtC, bcat, (void*)proj);

    // bilinear sampling + softmax-weighted sum -> out_h bf16 [8000][256]
    ms_sample_kernel<<<N_BATCH * LEN_Q, 512, 0, stream>>>(
        value, proj, refp, out_h);

    // out = out_h @ W_out + b_out -> d_out f32 [8000][256]
    gemm_k256<4, true, false><<<(N_BATCH * LEN_Q) / 16, 256, 0, stream>>>(
        out_h, WtO, b_out, d_out);
}

// Round 14
// 119.852 us; speedup vs baseline: 1.1667x; 1.1667x over previous
//
#include <hip/hip_runtime.h>
#include <hip/hip_bf16.h>

#define D_MODEL 256
#define N_HEADS 8
#define D_HEAD 32
#define N_LEVELS 4
#define N_POINTS 4
#define LEN_IN 21760
#define N_BATCH 8
#define LEN_Q 1000

typedef __attribute__((ext_vector_type(8))) short short8;
typedef __attribute__((ext_vector_type(4))) float f32x4;
typedef __attribute__((ext_vector_type(4))) unsigned int u32x4;

typedef const __attribute__((address_space(1))) void* gp1;
typedef __attribute__((address_space(3))) void* lp3;

__device__ __forceinline__ unsigned short f2bf(float f) {
    unsigned int u = __float_as_uint(f);
    u += 0x7FFFu + ((u >> 16) & 1u);   // RNE
    return (unsigned short)(u >> 16);
}
__device__ __forceinline__ float bf2f(unsigned short s) {
    return __uint_as_float(((unsigned int)s) << 16);
}
__device__ __forceinline__ unsigned int cvtpk(float lo, float hi) {
    unsigned int r;
    asm("v_cvt_pk_bf16_f32 %0, %1, %2" : "=v"(r) : "v"(lo), "v"(hi));
    return r;
}

// ---------------------------------------------------------------------------
// prep:
//   WtVp [16][16][64][8] bf16 <- W_val^T packed MFMA-fragment-major
//   WtC  [384][256] bf16      <- [W_off | W_attn]^T row-major
//   WtO  [256][256] bf16      <- W_out^T row-major
//   bcat [384] f32            <- [b_off | b_attn]
// ---------------------------------------------------------------------------
__global__ __launch_bounds__(256) void prep_kernel(
    const float* __restrict__ Wv, const float* __restrict__ Wo,
    const float* __restrict__ Wa, const float* __restrict__ Wu,
    const float* __restrict__ boff, const float* __restrict__ battn,
    unsigned short* __restrict__ WtVp, unsigned short* __restrict__ WtC,
    unsigned short* __restrict__ WtO, float* __restrict__ bcat)
{
    int idx = blockIdx.x * 256 + threadIdx.x;
    if (idx < 65536) {
        int j = idx & 7, lane = (idx >> 3) & 63, nf = (idx >> 9) & 15, ks = idx >> 13;
        int col = nf * 16 + (lane & 15);
        int k = ks * 32 + (lane >> 4) * 8 + j;
        WtVp[idx] = f2bf(Wv[k * 256 + col]);
    } else if (idx < 65536 + 98304) {
        int j = idx - 65536;
        int n = j >> 8, k = j & 255;
        float s = (n < 256) ? Wo[k * 256 + n] : Wa[k * 128 + (n - 256)];
        WtC[j] = f2bf(s);
    } else if (idx < 65536 + 98304 + 65536) {
        int j = idx - (65536 + 98304);
        int n = j >> 8, k = j & 255;
        WtO[j] = f2bf(Wu[k * 256 + n]);
    } else if (idx < 65536 + 98304 + 65536 + 384) {
        int j = idx - (65536 + 98304 + 65536);
        bcat[j] = (j < 256) ? boff[j] : battn[j - 256];
    }
}

// ---------------------------------------------------------------------------
// Value GEMM v8 = R10 champion (v4: BM=64, BK=64, 4 waves, counted vmcnt)
// + LDS-transpose epilogue producing fully-coalesced 64B-line stores.
// Per k-step FIFO unchanged: [B(kt) x8][S(kt+1) x4] -> vmcnt(12) (tail 8).
// Epilogue: acc -> bf16 scalars into a 528B-row-padded LDS tile (barrier),
// then each thread copies 8 linear 16B chunks: ds_read_b128 +
// global_store_dwordx4 -> every store instruction covers complete lines.
// ---------------------------------------------------------------------------
__global__ __launch_bounds__(256) void gemm_value(
    const float* __restrict__ A,
    const unsigned short* __restrict__ Bp,   // [16][16][64][8] bf16
    const float* __restrict__ bias,
    unsigned short* __restrict__ C)
{
    // 33,792B: k-loop uses first 32KB as 2x16KB f32 double-buffer;
    // epilogue reuses all of it as a 64-row x 528B bf16 tile (after barrier).
    __shared__ __align__(16) char smem[33792];

    const int tid = threadIdx.x;
    const int wave = tid >> 6, lane = tid & 63;
    const int lhi = lane >> 4, llo = lane & 15;
    const int mBase = blockIdx.x * 64;

    // staging: instr i writes LDS granules [i*256+tid] (16B each);
    // logical row = i*16+(tid>>4); physical granule pg=tid&15 holds
    // logical cg = pg ^ (row&15) -> source col granule = (tid&15)^((tid>>4)&15)
    const int srow = tid >> 4;
    const int scg = (tid & 15) ^ (srow & 15);
    const char* Ab = (const char*)(A + (size_t)mBase * 256);

#define STG(bi, kt) { \
    const char* s_ = Ab + (size_t)(kt) * 256 + (size_t)srow * 1024 + scg * 16; \
    char* d_ = smem + (bi) * 16384 + tid * 16; \
    __builtin_amdgcn_global_load_lds((gp1)(const void*)(s_),         (lp3)(d_),         16, 0, 0); \
    __builtin_amdgcn_global_load_lds((gp1)(const void*)(s_ + 16384), (lp3)(d_ + 4096),  16, 0, 0); \
    __builtin_amdgcn_global_load_lds((gp1)(const void*)(s_ + 32768), (lp3)(d_ + 8192),  16, 0, 0); \
    __builtin_amdgcn_global_load_lds((gp1)(const void*)(s_ + 49152), (lp3)(d_ + 12288), 16, 0, 0); }

    f32x4 acc[4][4];
#pragma unroll
    for (int mf = 0; mf < 4; ++mf)
#pragma unroll
        for (int n = 0; n < 4; ++n)
            acc[mf][n] = (f32x4){0.f, 0.f, 0.f, 0.f};

    STG(0, 0);   // prologue

#pragma unroll
    for (int kt = 0; kt < 4; ++kt) {
        const int cur = kt & 1;

        // B fragments for both k-slices of this step (issued BEFORE stage)
        short8 b[2][4];
#pragma unroll
        for (int ksi = 0; ksi < 2; ++ksi)
#pragma unroll
            for (int n = 0; n < 4; ++n)
                b[ksi][n] = *reinterpret_cast<const short8*>(
                    Bp + ((size_t)((kt * 2 + ksi) * 16 + wave * 4 + n) * 64 + lane) * 8);

        if (kt < 3) STG(cur ^ 1, kt + 1);

        __builtin_amdgcn_sched_barrier(0);
        if (kt < 3) asm volatile("s_waitcnt vmcnt(12)" ::: "memory");
        else        asm volatile("s_waitcnt vmcnt(8)" ::: "memory");
        __builtin_amdgcn_sched_barrier(0);
        __builtin_amdgcn_s_barrier();
        __builtin_amdgcn_sched_barrier(0);

        // compute: 4 mf x 2 ksi x 4 n MFMAs; A frags via swizzled ds_read
#pragma unroll
        for (int mf = 0; mf < 4; ++mf) {
            const int row = mf * 16 + llo;
            const char* rbase = smem + cur * 16384 + row * 256;
#pragma unroll
            for (int ksi = 0; ksi < 2; ++ksi) {
                const int cg0 = ksi * 8 + lhi * 2;
                f32x4 flo = *reinterpret_cast<const f32x4*>(rbase + ((cg0 ^ llo) << 4));
                f32x4 fhi = *reinterpret_cast<const f32x4*>(rbase + (((cg0 + 1) ^ llo) << 4));
                u32x4 pk;
                pk[0] = cvtpk(flo[0], flo[1]);
                pk[1] = cvtpk(flo[2], flo[3]);
                pk[2] = cvtpk(fhi[0], fhi[1]);
                pk[3] = cvtpk(fhi[2], fhi[3]);
                short8 af = __builtin_bit_cast(short8, pk);
#pragma unroll
                for (int n = 0; n < 4; ++n)
                    acc[mf][n] = __builtin_amdgcn_mfma_f32_16x16x32_bf16(
                        af, b[ksi][n], acc[mf][n], 0, 0, 0);
            }
        }

        __builtin_amdgcn_sched_barrier(0);
        __builtin_amdgcn_s_barrier();
        __builtin_amdgcn_sched_barrier(0);
    }
#undef STG

    // ---- epilogue E1: pack bf16 into padded LDS tile (row stride 528B) ----
    // D layout: col = lane&15 (+n*16+wave*64), row = mf*16 + 4*(lane>>4) + r
    float bb[4];
#pragma unroll
    for (int n = 0; n < 4; ++n) bb[n] = bias[wave * 64 + n * 16 + llo];

    unsigned short* t16 = reinterpret_cast<unsigned short*>(smem);
#pragma unroll
    for (int mf = 0; mf < 4; ++mf) {
        const int r0 = mf * 16 + lhi * 4;
#pragma unroll
        for (int n = 0; n < 4; ++n) {
            const int col = wave * 64 + n * 16 + llo;
            unsigned int p01 = cvtpk(acc[mf][n][0] + bb[n], acc[mf][n][1] + bb[n]);
            unsigned int p23 = cvtpk(acc[mf][n][2] + bb[n], acc[mf][n][3] + bb[n]);
            t16[(r0 + 0) * 264 + col] = (unsigned short)(p01 & 0xFFFFu);
            t16[(r0 + 1) * 264 + col] = (unsigned short)(p01 >> 16);
            t16[(r0 + 2) * 264 + col] = (unsigned short)(p23 & 0xFFFFu);
            t16[(r0 + 3) * 264 + col] = (unsigned short)(p23 >> 16);
        }
    }
    __syncthreads();

    // ---- epilogue E2: linear re-read + fully-coalesced dwordx4 stores ----
#pragma unroll
    for (int c = 0; c < 8; ++c) {
        const int idx = c * 256 + tid;          // 16B chunk id, 0..2047
        const int row = idx >> 5;
        const int off = (idx & 31) << 4;        // byte offset within row
        u32x4 v = *reinterpret_cast<const u32x4*>(smem + row * 528 + off);
        *reinterpret_cast<u32x4*>(
            (char*)C + ((size_t)mBase + row) * 512 + off) = v;
    }
}

// ---------------------------------------------------------------------------
// Generic K=256 MFMA GEMM, BM=16: C[M][N] = A[M][256] @ Wt^T + bias
// ---------------------------------------------------------------------------
template<int NF, bool ABF16, bool OBF16>
__global__ __launch_bounds__(256) void gemm_k256(
    const void* __restrict__ Av, const unsigned short* __restrict__ Wt,
    const float* __restrict__ bias, void* __restrict__ Cv)
{
    const int wave = threadIdx.x >> 6;
    const int lane = threadIdx.x & 63;
    const int lhi = lane >> 4, llo = lane & 15;
    const int mBase = blockIdx.x * 16;
    const int colBase = wave * (NF * 16);
    const int N = NF * 64;

    f32x4 acc[NF];
#pragma unroll
    for (int n = 0; n < NF; ++n)
        acc[n] = (f32x4){0.f, 0.f, 0.f, 0.f};

#pragma unroll
    for (int ks = 0; ks < 8; ++ks) {
        const int kk = ks * 32 + lhi * 8;
        short8 a;
        if (ABF16) {
            a = *reinterpret_cast<const short8*>(
                (const unsigned short*)Av + (size_t)(mBase + llo) * 256 + kk);
        } else {
            const float* ap = (const float*)Av + (size_t)(mBase + llo) * 256 + kk;
            f32x4 f0 = *reinterpret_cast<const f32x4*>(ap);
            f32x4 f1 = *reinterpret_cast<const f32x4*>(ap + 4);
            u32x4 pk;
            pk[0] = cvtpk(f0[0], f0[1]);
            pk[1] = cvtpk(f0[2], f0[3]);
            pk[2] = cvtpk(f1[0], f1[1]);
            pk[3] = cvtpk(f1[2], f1[3]);
            a = __builtin_bit_cast(short8, pk);
        }
        short8 b[NF];
#pragma unroll
        for (int n = 0; n < NF; ++n) {
            const unsigned short* bp =
                Wt + (size_t)(colBase + n * 16 + llo) * 256 + kk;
            b[n] = *reinterpret_cast<const short8*>(bp);
        }
#pragma unroll
        for (int n = 0; n < NF; ++n)
            acc[n] = __builtin_amdgcn_mfma_f32_16x16x32_bf16(
                a, b[n], acc[n], 0, 0, 0);
    }

    const int row0 = mBase + lhi * 4;
#pragma unroll
    for (int n = 0; n < NF; ++n) {
        const int col = colBase + n * 16 + llo;
        const float bb = bias[col];
#pragma unroll
        for (int r = 0; r < 4; ++r) {
            float v = acc[n][r] + bb;
            size_t idx = (size_t)(row0 + r) * N + col;
            if (OBF16) ((unsigned short*)Cv)[idx] = f2bf(v);
            else       ((float*)Cv)[idx] = v;
        }
    }
}

// ---------------------------------------------------------------------------
// Sampling v5: task-per-lane; float2 merged proj/refp loads; gathers issued
// before the softmax shfl chain (softmax hides under gather latency).
// ---------------------------------------------------------------------------
__global__ __launch_bounds__(512) void ms_sample_kernel(
    const unsigned short* __restrict__ value,  // [8*21760][256] bf16
    const float* __restrict__ proj,            // [8000][384] f32
    const float* __restrict__ refp,            // [8][1000][4][2] f32
    unsigned short* __restrict__ out_h)        // [8000][256] bf16
{
    const int bid = blockIdx.x;
    const int b = bid & 7;                     // XCD-pinned batch
    const int q = bid >> 3;
    const int bq = b * LEN_Q + q;

    const int h = threadIdx.x >> 6;            // 0..7
    const int lane = threadIdx.x & 63;
    const int task = lane >> 2;                // 0..15 = l*4+p
    const int l = task >> 2;
    const int qd = lane & 3;                   // dim quarter

    const float* prow = proj + (size_t)bq * 384;

    // ---- address math for this lane's sample ----
    const int Wl = 128 >> l;
    const int st = (65536 - (65536 >> (l << 1))) / 3;  // level start row

    const float2 dxy = *reinterpret_cast<const float2*>(prow + h * 32 + 2 * task);
    const float2 rxy = *reinterpret_cast<const float2*>(refp + ((size_t)bq * 4 + l) * 2);

    const float Wlf = (float)Wl;
    const float x = rxy.x * Wlf + dxy.x - 0.5f;
    const float y = rxy.y * Wlf + dxy.y - 0.5f;
    const float x0f = floorf(x), y0f = floorf(y);
    const int x0 = (int)x0f, y0 = (int)y0f;
    const float wx1 = x - x0f, wy1 = y - y0f;
    const float wx0 = 1.f - wx1, wy0 = 1.f - wy1;

    const int x0c = min(max(x0, 0), Wl - 1);
    const int x1c = min(max(x0 + 1, 0), Wl - 1);
    const int y0c = min(max(y0, 0), Wl - 1);
    const int y1c = min(max(y0 + 1, 0), Wl - 1);
    const float fx0 = (x0 >= 0 && x0 < Wl) ? 1.f : 0.f;
    const float fx1 = (x0 + 1 >= 0 && x0 + 1 < Wl) ? 1.f : 0.f;
    const float fy0 = (y0 >= 0 && y0 < Wl) ? 1.f : 0.f;
    const float fy1 = (y0 + 1 >= 0 && y0 + 1 < Wl) ? 1.f : 0.f;

    const int rr0 = st + y0c * Wl, rr1 = st + y1c * Wl;
    const int r00 = rr0 + x0c, r01 = rr0 + x1c;
    const int r10 = rr1 + x0c, r11 = rr1 + x1c;

    // ---- issue all 4 gathers ----
    const char* vb = (const char*)value + (size_t)b * LEN_IN * 512
                   + h * 64 + qd * 16;
    u32x4 v0 = *reinterpret_cast<const u32x4*>(vb + (size_t)r00 * 512);
    u32x4 v1 = *reinterpret_cast<const u32x4*>(vb + (size_t)r01 * 512);
    u32x4 v2 = *reinterpret_cast<const u32x4*>(vb + (size_t)r10 * 512);
    u32x4 v3 = *reinterpret_cast<const u32x4*>(vb + (size_t)r11 * 512);

    // ---- softmax under gather shadow ----
    float lg = prow[256 + h * 16 + (lane & 15)];
    float mx = lg;
    mx = fmaxf(mx, __shfl_xor(mx, 1, 16));
    mx = fmaxf(mx, __shfl_xor(mx, 2, 16));
    mx = fmaxf(mx, __shfl_xor(mx, 4, 16));
    mx = fmaxf(mx, __shfl_xor(mx, 8, 16));
    float e = __expf(lg - mx);
    float den = e;
    den += __shfl_xor(den, 1, 16);
    den += __shfl_xor(den, 2, 16);
    den += __shfl_xor(den, 4, 16);
    den += __shfl_xor(den, 8, 16);
    const float wsm = e / den;
    const float ws = __shfl(wsm, task, 16);    // this lane's task weight

    float wgt[4];
    wgt[0] = ws * wy0 * wx0 * fy0 * fx0;
    wgt[1] = ws * wy0 * wx1 * fy0 * fx1;
    wgt[2] = ws * wy1 * wx0 * fy1 * fx0;
    wgt[3] = ws * wy1 * wx1 * fy1 * fx1;

    // ---- weighted accumulate: 8 dims per lane ----
    float acc[8];
#pragma unroll
    for (int j = 0; j < 8; ++j) acc[j] = 0.f;
#pragma unroll
    for (int n = 0; n < 4; ++n) {
        const u32x4 v = (n == 0) ? v0 : (n == 1) ? v1 : (n == 2) ? v2 : v3;
        const float wn = wgt[n];
#pragma unroll
        for (int j = 0; j < 4; ++j) {
            const unsigned int u = v[j];
            acc[2 * j]     += wn * bf2f((unsigned short)(u & 0xFFFFu));
            acc[2 * j + 1] += wn * bf2f((unsigned short)(u >> 16));
        }
    }

    // ---- reduce over the 16 tasks (stride-4 lane sets) ----
#pragma unroll
    for (int j = 0; j < 8; ++j) {
        acc[j] += __shfl_xor(acc[j], 4, 64);
        acc[j] += __shfl_xor(acc[j], 8, 64);
        acc[j] += __shfl_xor(acc[j], 16, 64);
        acc[j] += __shfl_xor(acc[j], 32, 64);
    }

    if (task == 0) {
        u32x4 o;
#pragma unroll
        for (int j = 0; j < 4; ++j)
            o[j] = (unsigned int)f2bf(acc[2 * j]) |
                   ((unsigned int)f2bf(acc[2 * j + 1]) << 16);
        *reinterpret_cast<u32x4*>(
            out_h + (size_t)bq * 256 + h * 32 + qd * 8) = o;
    }
}

// ---------------------------------------------------------------------------
extern "C" void kernel_launch(void* const* d_in, const int* in_sizes, int n_in,
                              void* d_out, int out_size, void* d_ws, size_t ws_size,
                              hipStream_t stream)
{
    const float* query  = (const float*)d_in[0];
    const float* refp   = (const float*)d_in[1];
    const float* inpf   = (const float*)d_in[2];
    const float* W_off  = (const float*)d_in[5];
    const float* b_off  = (const float*)d_in[6];
    const float* W_attn = (const float*)d_in[7];
    const float* b_attn = (const float*)d_in[8];
    const float* W_val  = (const float*)d_in[9];
    const float* b_val  = (const float*)d_in[10];
    const float* W_out  = (const float*)d_in[11];
    const float* b_out  = (const float*)d_in[12];

    char* ws = (char*)d_ws;
    unsigned short* value = (unsigned short*)(ws);                    // 89,128,960 B
    float*          proj  = (float*)(ws + 89128960);                  // 12,288,000 B
    unsigned short* out_h = (unsigned short*)(ws + 89128960 + 12288000); // 4,096,000 B
    unsigned short* WtVp  = (unsigned short*)(ws + 109608960);        //    131,072 B
    unsigned short* WtC   = (unsigned short*)(ws + 109740032);        //    196,608 B
    unsigned short* WtO   = (unsigned short*)(ws + 109936640);        //    131,072 B
    float*          bcat  = (float*)(ws + 110067712);                 //      1,536 B

    prep_kernel<<<898, 256, 0, stream>>>(W_val, W_off, W_attn, W_out,
                                         b_off, b_attn, WtVp, WtC, WtO, bcat);

    // value = input_flatten @ W_val + b_val -> bf16 [174080][256]
    gemm_value<<<(N_BATCH * LEN_IN) / 64, 256, 0, stream>>>(
        inpf, WtVp, b_val, value);

    // proj = query @ [W_off|W_attn] + bias -> f32 [8000][384]
    gemm_k256<6, false, false><<<(N_BATCH * LEN_Q) / 16, 256, 0, stream>>>(
        query, WtC, bcat, (void*)proj);

    // bilinear sampling + softmax-weighted sum -> out_h bf16 [8000][256]
    ms_sample_kernel<<<N_BATCH * LEN_Q, 512, 0, stream>>>(
        value, proj, refp, out_h);

    // out = out_h @ W_out + b_out -> d_out f32 [8000][256]
    gemm_k256<4, true, false><<<(N_BATCH * LEN_Q) / 16, 256, 0, stream>>>(
        out_h, WtO, b_out, d_out);
}